// Round 1
// baseline (641.657 us; speedup 1.0000x reference)
//
#include <hip/hip_runtime.h>

typedef __bf16 bf16_t;
typedef bf16_t bf16x8 __attribute__((ext_vector_type(8)));
typedef float f32x4 __attribute__((ext_vector_type(4)));

#define MFMA16(a, b, c) __builtin_amdgcn_mfma_f32_16x16x32_bf16(a, b, c, 0, 0, 0)

constexpr int B_ = 2, S_ = 2048, H_ = 2048, NH = 32, NKV = 8, HD = 64;
constexpr int NQKV = NH * HD + 2 * NKV * HD;   // 3072
constexpr int M_ROWS = B_ * S_;                // 4096
constexpr float QSCALE = 0.125f * 1.4426950408889634f;  // fold score-scale * log2(e) into q

// ---------------- f32 -> bf16 convert (8 elems/thread) ----------------
__global__ __launch_bounds__(256) void cvt_kernel(const float* __restrict__ in,
                                                  bf16_t* __restrict__ out, int n8) {
  int i = blockIdx.x * 256 + threadIdx.x;
  if (i >= n8) return;
  const float4* p = (const float4*)(in + (size_t)i * 8);
  float4 a = p[0], b = p[1];
  bf16x8 o;
  o[0] = (bf16_t)a.x; o[1] = (bf16_t)a.y; o[2] = (bf16_t)a.z; o[3] = (bf16_t)a.w;
  o[4] = (bf16_t)b.x; o[5] = (bf16_t)b.y; o[6] = (bf16_t)b.z; o[7] = (bf16_t)b.w;
  *(bf16x8*)(out + (size_t)i * 8) = o;
}

// ---------------- GEMM: C(MxN) = A(MxK) * B(NxK)^T, bf16 in, f32 acc ----------------
// 128x128 tile, BK=32, 4 waves (2x2), each wave 64x64 = 4x4 MFMA frags.
// Reg-staged LDS, double buffered, 1 barrier per K-step.
template <bool OUT_BF16>
__global__ __launch_bounds__(256) void gemm_bt(const bf16_t* __restrict__ A,
                                               const bf16_t* __restrict__ Bm,
                                               float* __restrict__ Cf,
                                               bf16_t* __restrict__ Cb,
                                               int M, int N, int K) {
  __shared__ bf16_t As[2][128 * 32];
  __shared__ bf16_t Bs[2][128 * 32];
  const int t = threadIdx.x;
  const int lane = t & 63, w = t >> 6;
  const int l15 = lane & 15, l4 = lane >> 4;
  const int wm = w >> 1, wn = w & 1;
  const long Ar0 = (long)blockIdx.y * 128;
  const long Br0 = (long)blockIdx.x * 128;
  const int nt = K >> 5;

  const bf16_t* ga = A + (Ar0 + (t >> 2)) * (long)K + (t & 3) * 8;
  const bf16_t* gb = Bm + (Br0 + (t >> 2)) * (long)K + (t & 3) * 8;
  const long rstep = 64L * K;

  bf16x8 va0, va1, vb0, vb1;

  auto loadg = [&](int kt) {
    const bf16_t* pa = ga + kt * 32;
    const bf16_t* pb = gb + kt * 32;
    va0 = *(const bf16x8*)pa;
    va1 = *(const bf16x8*)(pa + rstep);
    vb0 = *(const bf16x8*)pb;
    vb1 = *(const bf16x8*)(pb + rstep);
  };
  auto storelds = [&](int buf) {
    *(bf16x8*)&As[buf][t * 8] = va0;
    *(bf16x8*)&As[buf][2048 + t * 8] = va1;
    *(bf16x8*)&Bs[buf][t * 8] = vb0;
    *(bf16x8*)&Bs[buf][2048 + t * 8] = vb1;
  };

  f32x4 acc[4][4] = {};
  loadg(0);
  storelds(0);
  __syncthreads();
  int cur = 0;
  for (int kt = 0; kt < nt; ++kt) {
    if (kt + 1 < nt) loadg(kt + 1);
    bf16x8 af[4], bfr[4];
#pragma unroll
    for (int mf = 0; mf < 4; ++mf)
      af[mf] = *(const bf16x8*)&As[cur][(wm * 64 + mf * 16 + l15) * 32 + l4 * 8];
#pragma unroll
    for (int nf = 0; nf < 4; ++nf)
      bfr[nf] = *(const bf16x8*)&Bs[cur][(wn * 64 + nf * 16 + l15) * 32 + l4 * 8];
#pragma unroll
    for (int mf = 0; mf < 4; ++mf)
#pragma unroll
      for (int nf = 0; nf < 4; ++nf)
        acc[mf][nf] = MFMA16(af[mf], bfr[nf], acc[mf][nf]);
    if (kt + 1 < nt) storelds(cur ^ 1);
    __syncthreads();
    cur ^= 1;
  }
  // epilogue: C/D layout col = lane&15, row = (lane>>4)*4 + reg
#pragma unroll
  for (int mf = 0; mf < 4; ++mf)
#pragma unroll
    for (int nf = 0; nf < 4; ++nf)
#pragma unroll
      for (int r = 0; r < 4; ++r) {
        long row = Ar0 + wm * 64 + mf * 16 + l4 * 4 + r;
        long col = Br0 + wn * 64 + nf * 16 + l15;
        float v = acc[mf][nf][r];
        if (OUT_BF16)
          Cb[row * N + col] = (bf16_t)v;
        else
          Cf[row * N + col] = v;
      }
}

// ---------------- RoPE in-place on q,k sections of qkv; fold QSCALE into q ----------------
__global__ __launch_bounds__(256) void rope_kernel(bf16_t* __restrict__ qkv,
                                                   const float* __restrict__ cosb,
                                                   const float* __restrict__ sinb) {
  long idx = (long)blockIdx.x * 256 + threadIdx.x;  // (b*S+s, head40, d32)
  int d = (int)(idx & 31);
  long rest = idx >> 5;
  int head = (int)(rest % 40);
  long bs = rest / 40;
  long base = bs * NQKV + (head < 32 ? head * 64 : NH * HD + (head - 32) * 64);
  float c = cosb[bs * 64 + d];
  float sn = sinb[bs * 64 + d];
  float c2 = cosb[bs * 64 + d + 32];
  float s2 = sinb[bs * 64 + d + 32];
  float x1 = (float)qkv[base + d];
  float x2 = (float)qkv[base + d + 32];
  float y1 = x1 * c - x2 * sn;
  float y2 = x2 * c2 + x1 * s2;
  if (head < 32) { y1 *= QSCALE; y2 *= QSCALE; }
  qkv[base + d] = (bf16_t)y1;
  qkv[base + d + 32] = (bf16_t)y2;
}

// ---------------- V transpose: qkv v-section -> vT[b][kvh][d][s] ----------------
__global__ __launch_bounds__(256) void v_transpose(const bf16_t* __restrict__ qkv,
                                                   bf16_t* __restrict__ vT) {
  long idx = (long)blockIdx.x * 256 + threadIdx.x;  // total 2*8*64*2048
  int s = (int)(idx & 2047);
  long rest = idx >> 11;
  int d = (int)(rest & 63);
  rest >>= 6;
  int kvh = (int)(rest & 7);
  int b = (int)(rest >> 3);
  vT[idx] = qkv[((long)(b * S_ + s)) * NQKV + NH * HD + NKV * HD + kvh * 64 + d];
}

// ---------------- flash attention, causal, GQA ----------------
// grid (S/64, NH, B), 4 waves; wave w owns q rows qt*64 + w*16 .. +15.
__global__ __launch_bounds__(256) void attn_kernel(const bf16_t* __restrict__ qkv,
                                                   const bf16_t* __restrict__ vT,
                                                   bf16_t* __restrict__ y) {
  const int qt = blockIdx.x;
  const int h = blockIdx.y;
  const int b = blockIdx.z;
  const int kvh = h >> 2;  // jnp.repeat: head h uses kv head h/4
  const int t = threadIdx.x, lane = t & 63, w = t >> 6;
  const int l15 = lane & 15, l4 = lane >> 4;
  const int qrow0 = qt * 64 + w * 16;

  __shared__ bf16_t p_lds[4][16][64];

  // Q fragments (A-op): row = lane&15, k(d) = ks*32 + (lane>>4)*8 + j
  const bf16_t* qp = qkv + ((long)(b * S_ + qrow0 + l15)) * NQKV + h * 64 + l4 * 8;
  bf16x8 qf0 = *(const bf16x8*)qp;
  bf16x8 qf1 = *(const bf16x8*)(qp + 32);

  const bf16_t* kp = qkv + (long)b * S_ * NQKV + NH * HD + kvh * 64 + l4 * 8;
  const bf16_t* vp = vT + ((long)(b * NKV + kvh) * 64 + l15) * S_ + l4 * 8;

  f32x4 o_acc[4] = {};
  float m_r[4], l_r[4];
#pragma unroll
  for (int r = 0; r < 4; ++r) { m_r[r] = -1e30f; l_r[r] = 0.f; }

  for (int kt = 0; kt <= qt; ++kt) {
    const int kv0 = kt * 64;
    f32x4 sa[4] = {};
    const bf16_t* kt0 = kp + (long)kv0 * NQKV;
#pragma unroll
    for (int ks = 0; ks < 2; ++ks) {
      bf16x8 qf = ks ? qf1 : qf0;
#pragma unroll
      for (int nf = 0; nf < 4; ++nf) {
        bf16x8 kf = *(const bf16x8*)(kt0 + (long)(nf * 16 + l15) * NQKV + ks * 32);
        sa[nf] = MFMA16(qf, kf, sa[nf]);
      }
    }
    if (kt == qt) {  // diagonal tile: mask kv > q
#pragma unroll
      for (int nf = 0; nf < 4; ++nf)
#pragma unroll
        for (int r = 0; r < 4; ++r) {
          int qr = qrow0 + l4 * 4 + r;
          int kc = kv0 + nf * 16 + l15;
          if (kc > qr) sa[nf][r] = -3.0e38f;
        }
    }
    // row max (row lives across 16 lanes of same l4-group, 4 frags)
    float pm[4];
#pragma unroll
    for (int r = 0; r < 4; ++r)
      pm[r] = fmaxf(fmaxf(sa[0][r], sa[1][r]), fmaxf(sa[2][r], sa[3][r]));
#pragma unroll
    for (int off = 1; off < 16; off <<= 1)
#pragma unroll
      for (int r = 0; r < 4; ++r) pm[r] = fmaxf(pm[r], __shfl_xor(pm[r], off, 64));

    float sc[4], rs[4];
#pragma unroll
    for (int r = 0; r < 4; ++r) {
      float mn = fmaxf(m_r[r], pm[r]);
      sc[r] = exp2f(m_r[r] - mn);
      m_r[r] = mn;
      rs[r] = 0.f;
    }
    // p = exp2(s - m); write P tile to per-wave LDS for A-frag re-layout
#pragma unroll
    for (int nf = 0; nf < 4; ++nf)
#pragma unroll
      for (int r = 0; r < 4; ++r) {
        float p = exp2f(sa[nf][r] - m_r[r]);
        rs[r] += p;
        p_lds[w][l4 * 4 + r][nf * 16 + l15] = (bf16_t)p;
      }
#pragma unroll
    for (int off = 1; off < 16; off <<= 1)
#pragma unroll
      for (int r = 0; r < 4; ++r) rs[r] += __shfl_xor(rs[r], off, 64);
#pragma unroll
    for (int r = 0; r < 4; ++r) l_r[r] = l_r[r] * sc[r] + rs[r];
#pragma unroll
    for (int nf = 0; nf < 4; ++nf)
#pragma unroll
      for (int r = 0; r < 4; ++r) o_acc[nf][r] *= sc[r];

    // PV: A = P (k=kv), B = V^T-resident (k=kv contiguous per lane)
#pragma unroll
    for (int ks = 0; ks < 2; ++ks) {
      bf16x8 pf = *(const bf16x8*)&p_lds[w][l15][ks * 32 + l4 * 8];
#pragma unroll
      for (int nf = 0; nf < 4; ++nf) {
        bf16x8 vf = *(const bf16x8*)(vp + (long)nf * 16 * S_ + kv0 + ks * 32);
        o_acc[nf] = MFMA16(pf, vf, o_acc[nf]);
      }
    }
  }
#pragma unroll
  for (int r = 0; r < 4; ++r) l_r[r] = 1.f / l_r[r];
  bf16_t* yp = y + ((long)(b * S_) + qrow0) * H_ + h * 64;
#pragma unroll
  for (int nf = 0; nf < 4; ++nf)
#pragma unroll
    for (int r = 0; r < 4; ++r)
      yp[(long)(l4 * 4 + r) * H_ + nf * 16 + l15] = (bf16_t)(o_acc[nf][r] * l_r[r]);
}

extern "C" void kernel_launch(void* const* d_in, const int* in_sizes, int n_in,
                              void* d_out, int out_size, void* d_ws, size_t ws_size,
                              hipStream_t stream) {
  const float* hs = (const float*)d_in[0];
  const float* cosb = (const float*)d_in[1];
  const float* sinb = (const float*)d_in[2];
  const float* Wq = (const float*)d_in[3];
  const float* Wk = (const float*)d_in[4];
  const float* Wv = (const float*)d_in[5];
  const float* Wo = (const float*)d_in[6];
  float* out = (float*)d_out;

  char* ws = (char*)d_ws;
  bf16_t* hsb  = (bf16_t*)(ws);                 // 4096*2048*2  = 16,777,216
  bf16_t* wqkv = (bf16_t*)(ws + 16777216);      // 3072*2048*2  = 12,582,912
  bf16_t* wo   = (bf16_t*)(ws + 29360128);      // 2048*2048*2  =  8,388,608
  bf16_t* qkv  = (bf16_t*)(ws + 37748736);      // 4096*3072*2  = 25,165,824
  bf16_t* vT   = (bf16_t*)(ws + 62914560);      // 2*8*64*2048*2 = 4,194,304
  bf16_t* yb   = (bf16_t*)(ws + 67108864);      // 4096*2048*2  = 16,777,216
                                                // total 83,886,080 B

  // converts
  cvt_kernel<<<4096, 256, 0, stream>>>(hs, hsb, 1048576);
  cvt_kernel<<<2048, 256, 0, stream>>>(Wq, wqkv, 524288);
  cvt_kernel<<<512, 256, 0, stream>>>(Wk, wqkv + 2048 * 2048, 131072);
  cvt_kernel<<<512, 256, 0, stream>>>(Wv, wqkv + 2560 * 2048, 131072);
  cvt_kernel<<<2048, 256, 0, stream>>>(Wo, wo, 524288);

  // qkv projection
  gemm_bt<true><<<dim3(24, 32), 256, 0, stream>>>(hsb, wqkv, nullptr, qkv,
                                                  M_ROWS, NQKV, H_);
  // rope (q scaled by 0.125*log2e)
  rope_kernel<<<20480, 256, 0, stream>>>(qkv, cosb, sinb);
  // v transpose
  v_transpose<<<8192, 256, 0, stream>>>(qkv, vT);
  // attention
  attn_kernel<<<dim3(32, 32, 2), 256, 0, stream>>>(qkv, vT, yb);
  // output projection
  gemm_bt<false><<<dim3(16, 32), 256, 0, stream>>>(yb, wo, out, nullptr,
                                                   M_ROWS, H_, H_);
}

// Round 2
// 312.690 us; speedup vs baseline: 2.0521x; 2.0521x over previous
//
#include <hip/hip_runtime.h>

typedef __bf16 bf16_t;
typedef bf16_t bf16x8 __attribute__((ext_vector_type(8)));
typedef bf16_t bf16x4 __attribute__((ext_vector_type(4)));
typedef float f32x4 __attribute__((ext_vector_type(4)));
typedef float f32x16 __attribute__((ext_vector_type(16)));

#define MFMA16(a, b, c) __builtin_amdgcn_mfma_f32_16x16x32_bf16(a, b, c, 0, 0, 0)
#define MFMA32(a, b, c) __builtin_amdgcn_mfma_f32_32x32x16_bf16(a, b, c, 0, 0, 0)

constexpr int B_ = 2, S_ = 2048, H_ = 2048, NH = 32, NKV = 8, HD = 64;
constexpr int NQKV = NH * HD + 2 * NKV * HD;   // 3072
constexpr int M_ROWS = B_ * S_;                // 4096
constexpr float QSCALE = 0.125f * 1.4426950408889634f;  // score-scale * log2(e) folded into q

// ---------------- f32 -> bf16 convert (8 elems/thread) ----------------
__global__ __launch_bounds__(256) void cvt_kernel(const float* __restrict__ in,
                                                  bf16_t* __restrict__ out, int n8) {
  int i = blockIdx.x * 256 + threadIdx.x;
  if (i >= n8) return;
  const float4* p = (const float4*)(in + (size_t)i * 8);
  float4 a = p[0], b = p[1];
  bf16x8 o;
  o[0] = (bf16_t)a.x; o[1] = (bf16_t)a.y; o[2] = (bf16_t)a.z; o[3] = (bf16_t)a.w;
  o[4] = (bf16_t)b.x; o[5] = (bf16_t)b.y; o[6] = (bf16_t)b.z; o[7] = (bf16_t)b.w;
  *(bf16x8*)(out + (size_t)i * 8) = o;
}

// ---------------- GEMM: C(MxN) = A(MxK) * B(NxK)^T, bf16 in, f32 acc ----------------
template <bool OUT_BF16>
__global__ __launch_bounds__(256) void gemm_bt(const bf16_t* __restrict__ A,
                                               const bf16_t* __restrict__ Bm,
                                               float* __restrict__ Cf,
                                               bf16_t* __restrict__ Cb,
                                               int M, int N, int K) {
  __shared__ bf16_t As[2][128 * 32];
  __shared__ bf16_t Bs[2][128 * 32];
  const int t = threadIdx.x;
  const int lane = t & 63, w = t >> 6;
  const int l15 = lane & 15, l4 = lane >> 4;
  const int wm = w >> 1, wn = w & 1;
  const long Ar0 = (long)blockIdx.y * 128;
  const long Br0 = (long)blockIdx.x * 128;
  const int nt = K >> 5;

  const bf16_t* ga = A + (Ar0 + (t >> 2)) * (long)K + (t & 3) * 8;
  const bf16_t* gb = Bm + (Br0 + (t >> 2)) * (long)K + (t & 3) * 8;
  const long rstep = 64L * K;

  bf16x8 va0, va1, vb0, vb1;

  auto loadg = [&](int kt) {
    const bf16_t* pa = ga + kt * 32;
    const bf16_t* pb = gb + kt * 32;
    va0 = *(const bf16x8*)pa;
    va1 = *(const bf16x8*)(pa + rstep);
    vb0 = *(const bf16x8*)pb;
    vb1 = *(const bf16x8*)(pb + rstep);
  };
  auto storelds = [&](int buf) {
    *(bf16x8*)&As[buf][t * 8] = va0;
    *(bf16x8*)&As[buf][2048 + t * 8] = va1;
    *(bf16x8*)&Bs[buf][t * 8] = vb0;
    *(bf16x8*)&Bs[buf][2048 + t * 8] = vb1;
  };

  f32x4 acc[4][4] = {};
  loadg(0);
  storelds(0);
  __syncthreads();
  int cur = 0;
  for (int kt = 0; kt < nt; ++kt) {
    if (kt + 1 < nt) loadg(kt + 1);
    bf16x8 af[4], bfr[4];
#pragma unroll
    for (int mf = 0; mf < 4; ++mf)
      af[mf] = *(const bf16x8*)&As[cur][(wm * 64 + mf * 16 + l15) * 32 + l4 * 8];
#pragma unroll
    for (int nf = 0; nf < 4; ++nf)
      bfr[nf] = *(const bf16x8*)&Bs[cur][(wn * 64 + nf * 16 + l15) * 32 + l4 * 8];
#pragma unroll
    for (int mf = 0; mf < 4; ++mf)
#pragma unroll
      for (int nf = 0; nf < 4; ++nf)
        acc[mf][nf] = MFMA16(af[mf], bfr[nf], acc[mf][nf]);
    if (kt + 1 < nt) storelds(cur ^ 1);
    __syncthreads();
    cur ^= 1;
  }
#pragma unroll
  for (int mf = 0; mf < 4; ++mf)
#pragma unroll
    for (int nf = 0; nf < 4; ++nf)
#pragma unroll
      for (int r = 0; r < 4; ++r) {
        long row = Ar0 + wm * 64 + mf * 16 + l4 * 4 + r;
        long col = Br0 + wn * 64 + nf * 16 + l15;
        float v = acc[mf][nf][r];
        if (OUT_BF16)
          Cb[row * N + col] = (bf16_t)v;
        else
          Cf[row * N + col] = v;
      }
}

// ---------------- RoPE in-place on q,k sections of qkv; fold QSCALE into q ----------------
__global__ __launch_bounds__(256) void rope_kernel(bf16_t* __restrict__ qkv,
                                                   const float* __restrict__ cosb,
                                                   const float* __restrict__ sinb) {
  long idx = (long)blockIdx.x * 256 + threadIdx.x;  // (b*S+s, head40, d32)
  int d = (int)(idx & 31);
  long rest = idx >> 5;
  int head = (int)(rest % 40);
  long bs = rest / 40;
  long base = bs * NQKV + (head < 32 ? head * 64 : NH * HD + (head - 32) * 64);
  float c = cosb[bs * 64 + d];
  float sn = sinb[bs * 64 + d];
  float c2 = cosb[bs * 64 + d + 32];
  float s2 = sinb[bs * 64 + d + 32];
  float x1 = (float)qkv[base + d];
  float x2 = (float)qkv[base + d + 32];
  float y1 = x1 * c - x2 * sn;
  float y2 = x2 * c2 + x1 * s2;
  if (head < 32) { y1 *= QSCALE; y2 *= QSCALE; }
  qkv[base + d] = (bf16_t)y1;
  qkv[base + d + 32] = (bf16_t)y2;
}

// ---------------- V transpose: qkv v-section -> vT[b][kvh][d][s] ----------------
__global__ __launch_bounds__(256) void v_transpose(const bf16_t* __restrict__ qkv,
                                                   bf16_t* __restrict__ vT) {
  long idx = (long)blockIdx.x * 256 + threadIdx.x;  // total 2*8*64*2048
  int s = (int)(idx & 2047);
  long rest = idx >> 11;
  int d = (int)(rest & 63);
  rest >>= 6;
  int kvh = (int)(rest & 7);
  int b = (int)(rest >> 3);
  vT[idx] = qkv[((long)(b * S_ + s)) * NQKV + NH * HD + NKV * HD + kvh * 64 + d];
}

__device__ __forceinline__ unsigned pkbf16(float lo, float hi) {
  union { bf16_t h[2]; unsigned u; } x;
  x.h[0] = (bf16_t)lo;
  x.h[1] = (bf16_t)hi;
  return x.u;
}

// ---------------- flash attention, causal, GQA — 32x32 MFMA, swapped operands ----------------
// grid (16, 32, 2) with qt reversed, 4 waves; wave w owns q rows q0+w*32 .. +31 (1 q-row per lane).
// QK^T: S^T = mfma(A=K, B=Q^T)  -> lane holds 32 S values for q = lane&31 (kv per C-row map)
// PV:   y^T = mfma(A=V^T, B=P^T)-> lane holds 32 y values for its own q (d per C-row map)
__global__ __launch_bounds__(256) void attn32_kernel(const bf16_t* __restrict__ qkv,
                                                     const bf16_t* __restrict__ vT,
                                                     bf16_t* __restrict__ y) {
  const int qt = 15 - blockIdx.x;          // heavy blocks first
  const int h = blockIdx.y;
  const int b = blockIdx.z;
  const int kvh = h >> 2;
  const int t = threadIdx.x, lane = t & 63, w = t >> 6;
  const int l31 = lane & 31, hd = lane >> 5;
  const long bS = (long)b * S_;
  const int q0 = qt * 128;
  const int q0w = q0 + w * 32;
  const int myq = q0w + l31;
  const int NT = qt * 2 + 2;               // kv tiles of 64 covering [0, q0+128)

  __shared__ __align__(16) bf16_t Klds[2][64 * 64];
  __shared__ __align__(16) bf16_t Vlds[2][64 * 64];

  // Q B-frags: col=lane&31=q, k(d) = ks*16 + hd*8 + j
  const bf16_t* qp = qkv + (bS + myq) * NQKV + h * 64 + hd * 8;
  bf16x8 qf[4];
#pragma unroll
  for (int ks = 0; ks < 4; ++ks) qf[ks] = *(const bf16x8*)(qp + ks * 16);

  const bf16_t* kbase = qkv + bS * NQKV + NH * HD + kvh * 64;       // [s][NQKV] K section
  const bf16_t* vbase = vT + ((long)(b * NKV + kvh)) * 64 * S_;     // [d][S]

  // staging: 256 threads x 2 chunks of 16B each for K and V
  const int row0 = t >> 3;           // 0..31 (second chunk row0+32)
  const int slot = t & 7;
  const int wslot8 = ((slot ^ (row0 & 7)) << 3);   // (row0+32)&7 == row0&7
  bf16x8 kreg0, kreg1, vreg0, vreg1;

  auto ldG = [&](int kv0) {
    const bf16_t* p = kbase + (long)(kv0 + row0) * NQKV + slot * 8;
    kreg0 = *(const bf16x8*)p;
    kreg1 = *(const bf16x8*)(p + 32L * NQKV);
    const bf16_t* pv = vbase + (long)row0 * S_ + kv0 + slot * 8;
    vreg0 = *(const bf16x8*)pv;
    vreg1 = *(const bf16x8*)(pv + 32L * S_);
  };
  auto wrLDS = [&](int buf) {
    *(bf16x8*)&Klds[buf][row0 * 64 + wslot8] = kreg0;
    *(bf16x8*)&Klds[buf][(row0 + 32) * 64 + wslot8] = kreg1;
    *(bf16x8*)&Vlds[buf][row0 * 64 + wslot8] = vreg0;
    *(bf16x8*)&Vlds[buf][(row0 + 32) * 64 + wslot8] = vreg1;
  };

  f32x16 yac[2] = {};
  float m = -1e30f, l = 0.f;

  ldG(0);
  wrLDS(0);
  __syncthreads();

  for (int kt = 0; kt < NT; ++kt) {
    const int buf = kt & 1;
    const int kv0 = kt * 64;
    if (kt + 1 < NT) ldG(kv0 + 64);          // issue next-tile global loads early

    if (kv0 <= q0w + 31) {                   // wave-uniform skip of fully-masked tiles
      // ---- QK^T ----
      f32x16 sac[2] = {};
#pragma unroll
      for (int ks = 0; ks < 4; ++ks)
#pragma unroll
        for (int kb = 0; kb < 2; ++kb) {
          const int row = kb * 32 + l31;
          const bf16x8 kf =
              *(const bf16x8*)&Klds[buf][row * 64 + (((2 * ks + hd) ^ (row & 7)) << 3)];
          sac[kb] = MFMA32(kf, qf[ks], sac[kb]);
        }
      // ---- causal mask (diagonal tiles only) ----
      if (kv0 + 63 > q0w) {
#pragma unroll
        for (int kb = 0; kb < 2; ++kb)
#pragma unroll
          for (int r = 0; r < 16; ++r) {
            const int kv = kv0 + kb * 32 + (r & 3) + 8 * (r >> 2) + 4 * hd;
            if (kv > myq) sac[kb][r] = -3.0e38f;
          }
      }
      // ---- online softmax (q row is lane-local; halves combined via 1 shfl) ----
      float pm4[8], sm4[8];
#pragma unroll
      for (int g = 0; g < 8; ++g) {
        const int kb = g >> 2, r = (g & 3) * 4;
        pm4[g] = fmaxf(fmaxf(sac[kb][r], sac[kb][r + 1]),
                       fmaxf(sac[kb][r + 2], sac[kb][r + 3]));
      }
      float pm = fmaxf(fmaxf(fmaxf(pm4[0], pm4[1]), fmaxf(pm4[2], pm4[3])),
                       fmaxf(fmaxf(pm4[4], pm4[5]), fmaxf(pm4[6], pm4[7])));
      pm = fmaxf(pm, __shfl_xor(pm, 32, 64));
      const float mnew = fmaxf(m, pm);
      const float sc = exp2f(m - mnew);
      m = mnew;
#pragma unroll
      for (int kb = 0; kb < 2; ++kb)
#pragma unroll
        for (int r = 0; r < 16; ++r) sac[kb][r] = exp2f(sac[kb][r] - m);
#pragma unroll
      for (int g = 0; g < 8; ++g) {
        const int kb = g >> 2, r = (g & 3) * 4;
        sm4[g] = (sac[kb][r] + sac[kb][r + 1]) + (sac[kb][r + 2] + sac[kb][r + 3]);
      }
      float rs = ((sm4[0] + sm4[1]) + (sm4[2] + sm4[3])) +
                 ((sm4[4] + sm4[5]) + (sm4[6] + sm4[7]));
      rs += __shfl_xor(rs, 32, 64);
      l = l * sc + rs;
      yac[0] *= sc;
      yac[1] *= sc;
      // ---- pack P^T B-frags in-register (cvt_pk + cross-half shfl) + PV ----
#pragma unroll
      for (int ks = 0; ks < 4; ++ks) {
        const int kb = ks >> 1;
        const int Bv = 8 * (ks & 1);
        const unsigned p0 = pkbf16(sac[kb][Bv + 0], sac[kb][Bv + 1]);
        const unsigned p1 = pkbf16(sac[kb][Bv + 2], sac[kb][Bv + 3]);
        const unsigned p2 = pkbf16(sac[kb][Bv + 4], sac[kb][Bv + 5]);
        const unsigned p3 = pkbf16(sac[kb][Bv + 6], sac[kb][Bv + 7]);
        const unsigned xf0 = hd ? p0 : p2, xf1 = hd ? p1 : p3;
        const unsigned rc0 = __shfl_xor(xf0, 32, 64);
        const unsigned rc1 = __shfl_xor(xf1, 32, 64);
        union { unsigned u[4]; bf16x8 v; } pu;
        pu.u[0] = hd ? rc0 : p0;
        pu.u[1] = hd ? rc1 : p1;
        pu.u[2] = hd ? p2 : rc0;
        pu.u[3] = hd ? p3 : rc1;
#pragma unroll
        for (int db = 0; db < 2; ++db) {
          const int row = db * 32 + l31;
          const bf16x8 vf =
              *(const bf16x8*)&Vlds[buf][row * 64 + (((2 * ks + hd) ^ (row & 7)) << 3)];
          yac[db] = MFMA32(vf, pu.v, yac[db]);
        }
      }
    }

    if (kt + 1 < NT) wrLDS(buf ^ 1);         // write-late: regs -> other LDS buffer
    __syncthreads();
  }

  // ---- epilogue: lane holds full y row for q = myq; d = db*32 + (r&3)+8*(r>>2)+4*hd ----
  const float inv = 1.f / l;
  bf16_t* yp = y + (bS + myq) * (long)H_ + h * 64;
#pragma unroll
  for (int db = 0; db < 2; ++db)
#pragma unroll
    for (int g = 0; g < 4; ++g) {
      bf16x4 o;
      o[0] = (bf16_t)(yac[db][4 * g + 0] * inv);
      o[1] = (bf16_t)(yac[db][4 * g + 1] * inv);
      o[2] = (bf16_t)(yac[db][4 * g + 2] * inv);
      o[3] = (bf16_t)(yac[db][4 * g + 3] * inv);
      *(bf16x4*)(yp + db * 32 + 8 * g + 4 * hd) = o;
    }
}

extern "C" void kernel_launch(void* const* d_in, const int* in_sizes, int n_in,
                              void* d_out, int out_size, void* d_ws, size_t ws_size,
                              hipStream_t stream) {
  const float* hs = (const float*)d_in[0];
  const float* cosb = (const float*)d_in[1];
  const float* sinb = (const float*)d_in[2];
  const float* Wq = (const float*)d_in[3];
  const float* Wk = (const float*)d_in[4];
  const float* Wv = (const float*)d_in[5];
  const float* Wo = (const float*)d_in[6];
  float* out = (float*)d_out;

  char* ws = (char*)d_ws;
  bf16_t* hsb  = (bf16_t*)(ws);                 // 16,777,216 B
  bf16_t* wqkv = (bf16_t*)(ws + 16777216);      // 12,582,912 B
  bf16_t* wo   = (bf16_t*)(ws + 29360128);      //  8,388,608 B
  bf16_t* qkv  = (bf16_t*)(ws + 37748736);      // 25,165,824 B
  bf16_t* vT   = (bf16_t*)(ws + 62914560);      //  4,194,304 B
  bf16_t* yb   = (bf16_t*)(ws + 67108864);      // 16,777,216 B

  cvt_kernel<<<4096, 256, 0, stream>>>(hs, hsb, 1048576);
  cvt_kernel<<<2048, 256, 0, stream>>>(Wq, wqkv, 524288);
  cvt_kernel<<<512, 256, 0, stream>>>(Wk, wqkv + 2048 * 2048, 131072);
  cvt_kernel<<<512, 256, 0, stream>>>(Wv, wqkv + 2560 * 2048, 131072);
  cvt_kernel<<<2048, 256, 0, stream>>>(Wo, wo, 524288);

  gemm_bt<true><<<dim3(24, 32), 256, 0, stream>>>(hsb, wqkv, nullptr, qkv,
                                                  M_ROWS, NQKV, H_);
  rope_kernel<<<20480, 256, 0, stream>>>(qkv, cosb, sinb);
  v_transpose<<<8192, 256, 0, stream>>>(qkv, vT);
  attn32_kernel<<<dim3(16, 32, 2), 256, 0, stream>>>(qkv, vT, yb);
  gemm_bt<false><<<dim3(16, 32), 256, 0, stream>>>(yb, wo, out, nullptr,
                                                   M_ROWS, H_, H_);
}

// Round 3
// 231.600 us; speedup vs baseline: 2.7705x; 1.3501x over previous
//
#include <hip/hip_runtime.h>

typedef __bf16 bf16_t;
typedef bf16_t bf16x8 __attribute__((ext_vector_type(8)));
typedef bf16_t bf16x4 __attribute__((ext_vector_type(4)));
typedef float f32x4 __attribute__((ext_vector_type(4)));
typedef float f32x16 __attribute__((ext_vector_type(16)));

#define MFMA16(a, b, c) __builtin_amdgcn_mfma_f32_16x16x32_bf16(a, b, c, 0, 0, 0)
#define MFMA32(a, b, c) __builtin_amdgcn_mfma_f32_32x32x16_bf16(a, b, c, 0, 0, 0)

#define GLOAD16(gsrc, ldst)                                            \
  __builtin_amdgcn_global_load_lds(                                    \
      (const __attribute__((address_space(1))) void*)(gsrc),           \
      (__attribute__((address_space(3))) void*)(ldst), 16, 0, 0)

constexpr int B_ = 2, S_ = 2048, H_ = 2048, NH = 32, NKV = 8, HD = 64;
constexpr int NQKV = NH * HD + 2 * NKV * HD;   // 3072
constexpr int M_ROWS = B_ * S_;                // 4096
constexpr float QSCALE = 0.125f * 1.4426950408889634f;  // score-scale * log2(e) folded into q

// ---------------- f32 -> bf16 convert (8 elems/thread) ----------------
__global__ __launch_bounds__(256) void cvt_kernel(const float* __restrict__ in,
                                                  bf16_t* __restrict__ out, int n8) {
  int i = blockIdx.x * 256 + threadIdx.x;
  if (i >= n8) return;
  const float4* p = (const float4*)(in + (size_t)i * 8);
  float4 a = p[0], b = p[1];
  bf16x8 o;
  o[0] = (bf16_t)a.x; o[1] = (bf16_t)a.y; o[2] = (bf16_t)a.z; o[3] = (bf16_t)a.w;
  o[4] = (bf16_t)b.x; o[5] = (bf16_t)b.y; o[6] = (bf16_t)b.z; o[7] = (bf16_t)b.w;
  *(bf16x8*)(out + (size_t)i * 8) = o;
}

// ---------------- GEMM: C(MxN) = A(MxK) * B(NxK)^T, bf16 in, f32 acc ----------------
// 128x128 tile, BK=32, 4 waves (2x2). global_load_lds(16B) staging, double-buffered,
// source-pre-swizzled LDS (slot ^= (row>>1)&3) for conflict-free ds_read_b128.
template <bool OUT_BF16>
__global__ __launch_bounds__(256) void gemm_bt(const bf16_t* __restrict__ A,
                                               const bf16_t* __restrict__ Bm,
                                               float* __restrict__ Cf,
                                               bf16_t* __restrict__ Cb,
                                               int M, int N, int K) {
  __shared__ __align__(16) bf16_t As[2][128 * 32];
  __shared__ __align__(16) bf16_t Bs[2][128 * 32];
  const int t = threadIdx.x;
  const int lane = t & 63, w = t >> 6;
  const int l15 = lane & 15, l4 = lane >> 4;
  const int wm = w >> 1, wn = w & 1;
  const long Ar0 = (long)blockIdx.y * 128;
  const long Br0 = (long)blockIdx.x * 128;
  const int nt = K >> 5;

  // staging: instruction i (= w*2+c) covers rows i*16 + (lane>>2), 16B per lane.
  // source col pre-swizzled so that swizzled reads see correct data (rule 21).
  const int scol = ((lane & 3) ^ ((lane >> 3) & 3)) * 8;
  const int srow = lane >> 2;
  auto stage = [&](int kt, int buf) {
#pragma unroll
    for (int c = 0; c < 2; ++c) {
      const int i = w * 2 + c;
      const bf16_t* gA = A + (Ar0 + i * 16 + srow) * (long)K + kt * 32 + scol;
      const bf16_t* gB = Bm + (Br0 + i * 16 + srow) * (long)K + kt * 32 + scol;
      GLOAD16(gA, &As[buf][i * 512]);
      GLOAD16(gB, &Bs[buf][i * 512]);
    }
  };

  f32x4 acc[4][4] = {};
  stage(0, 0);
  __syncthreads();
  int cur = 0;
  const int rsw = l4 ^ ((l15 >> 1) & 3);   // swizzled read slot
  for (int kt = 0; kt < nt; ++kt) {
    if (kt + 1 < nt) stage(kt + 1, cur ^ 1);
    bf16x8 af[4], bfr[4];
#pragma unroll
    for (int mf = 0; mf < 4; ++mf)
      af[mf] = *(const bf16x8*)&As[cur][(wm * 64 + mf * 16 + l15) * 32 + rsw * 8];
#pragma unroll
    for (int nf = 0; nf < 4; ++nf)
      bfr[nf] = *(const bf16x8*)&Bs[cur][(wn * 64 + nf * 16 + l15) * 32 + rsw * 8];
#pragma unroll
    for (int mf = 0; mf < 4; ++mf)
#pragma unroll
      for (int nf = 0; nf < 4; ++nf)
        acc[mf][nf] = MFMA16(af[mf], bfr[nf], acc[mf][nf]);
    __syncthreads();
    cur ^= 1;
  }
#pragma unroll
  for (int mf = 0; mf < 4; ++mf)
#pragma unroll
    for (int nf = 0; nf < 4; ++nf)
#pragma unroll
      for (int r = 0; r < 4; ++r) {
        long row = Ar0 + wm * 64 + mf * 16 + l4 * 4 + r;
        long col = Br0 + wn * 64 + nf * 16 + l15;
        float v = acc[mf][nf][r];
        if (OUT_BF16)
          Cb[row * N + col] = (bf16_t)v;
        else
          Cf[row * N + col] = v;
      }
}

// ---------------- RoPE in-place on q,k sections of qkv; fold QSCALE into q ----------------
__global__ __launch_bounds__(256) void rope_kernel(bf16_t* __restrict__ qkv,
                                                   const float* __restrict__ cosb,
                                                   const float* __restrict__ sinb) {
  long idx = (long)blockIdx.x * 256 + threadIdx.x;  // (b*S+s, head40, d32)
  int d = (int)(idx & 31);
  long rest = idx >> 5;
  int head = (int)(rest % 40);
  long bs = rest / 40;
  long base = bs * NQKV + (head < 32 ? head * 64 : NH * HD + (head - 32) * 64);
  float c = cosb[bs * 64 + d];
  float sn = sinb[bs * 64 + d];
  float c2 = cosb[bs * 64 + d + 32];
  float s2 = sinb[bs * 64 + d + 32];
  float x1 = (float)qkv[base + d];
  float x2 = (float)qkv[base + d + 32];
  float y1 = x1 * c - x2 * sn;
  float y2 = x2 * c2 + x1 * s2;
  if (head < 32) { y1 *= QSCALE; y2 *= QSCALE; }
  qkv[base + d] = (bf16_t)y1;
  qkv[base + d + 32] = (bf16_t)y2;
}

// ---------------- V transpose: qkv v-section -> vT[b][kvh][d][s] ----------------
__global__ __launch_bounds__(256) void v_transpose(const bf16_t* __restrict__ qkv,
                                                   bf16_t* __restrict__ vT) {
  long idx = (long)blockIdx.x * 256 + threadIdx.x;  // total 2*8*64*2048
  int s = (int)(idx & 2047);
  long rest = idx >> 11;
  int d = (int)(rest & 63);
  rest >>= 6;
  int kvh = (int)(rest & 7);
  int b = (int)(rest >> 3);
  vT[idx] = qkv[((long)(b * S_ + s)) * NQKV + NH * HD + NKV * HD + kvh * 64 + d];
}

__device__ __forceinline__ unsigned pkbf16(float lo, float hi) {
  union { bf16_t h[2]; unsigned u; } x;
  x.h[0] = (bf16_t)lo;
  x.h[1] = (bf16_t)hi;
  return x.u;
}

// ---------------- flash attention, causal, GQA — 32x32 MFMA, swapped operands ----------------
// grid (8, 32, 2); block x processes q-tiles {15-x, x} (equal 34 kv-tile-units per block).
// 4 waves; wave w owns q rows q0+w*32..+31 (1 q-row per lane).
__global__ __launch_bounds__(256) void attn32_kernel(const bf16_t* __restrict__ qkv,
                                                     const bf16_t* __restrict__ vT,
                                                     bf16_t* __restrict__ y) {
  const int h = blockIdx.y;
  const int b = blockIdx.z;
  const int kvh = h >> 2;
  const int t = threadIdx.x, lane = t & 63, w = t >> 6;
  const int l31 = lane & 31, hd = lane >> 5;
  const long bS = (long)b * S_;

  __shared__ __align__(16) bf16_t Klds[2][64 * 64];
  __shared__ __align__(16) bf16_t Vlds[2][64 * 64];

  const bf16_t* kbase = qkv + bS * NQKV + NH * HD + kvh * 64;       // [s][NQKV] K section
  const bf16_t* vbase = vT + ((long)(b * NKV + kvh)) * 64 * S_;     // [d][S]

  const int row0 = t >> 3;           // 0..31 (second chunk row0+32)
  const int slot = t & 7;
  const int wslot8 = ((slot ^ (row0 & 7)) << 3);
  bf16x8 kreg0, kreg1, vreg0, vreg1;

  auto ldG = [&](int kv0) {
    const bf16_t* p = kbase + (long)(kv0 + row0) * NQKV + slot * 8;
    kreg0 = *(const bf16x8*)p;
    kreg1 = *(const bf16x8*)(p + 32L * NQKV);
    const bf16_t* pv = vbase + (long)row0 * S_ + kv0 + slot * 8;
    vreg0 = *(const bf16x8*)pv;
    vreg1 = *(const bf16x8*)(pv + 32L * S_);
  };
  auto wrLDS = [&](int buf) {
    *(bf16x8*)&Klds[buf][row0 * 64 + wslot8] = kreg0;
    *(bf16x8*)&Klds[buf][(row0 + 32) * 64 + wslot8] = kreg1;
    *(bf16x8*)&Vlds[buf][row0 * 64 + wslot8] = vreg0;
    *(bf16x8*)&Vlds[buf][(row0 + 32) * 64 + wslot8] = vreg1;
  };

  for (int half = 0; half < 2; ++half) {
    const int qt = half ? (int)blockIdx.x : 15 - (int)blockIdx.x;
    const int q0w = qt * 128 + w * 32;
    const int myq = q0w + l31;
    const int NT = qt * 2 + 2;

    const bf16_t* qp = qkv + (bS + myq) * NQKV + h * 64 + hd * 8;
    bf16x8 qf[4];
#pragma unroll
    for (int ks = 0; ks < 4; ++ks) qf[ks] = *(const bf16x8*)(qp + ks * 16);

    f32x16 yac[2] = {};
    float m = -1e30f, l = 0.f;

    ldG(0);
    wrLDS(0);
    __syncthreads();

    for (int kt = 0; kt < NT; ++kt) {
      const int buf = kt & 1;
      const int kv0 = kt * 64;
      if (kt + 1 < NT) ldG(kv0 + 64);          // issue next-tile global loads early

      if (kv0 <= q0w + 31) {                   // wave-uniform skip of fully-masked tiles
        // ---- QK^T ----
        f32x16 sac[2] = {};
#pragma unroll
        for (int ks = 0; ks < 4; ++ks)
#pragma unroll
          for (int kb = 0; kb < 2; ++kb) {
            const int row = kb * 32 + l31;
            const bf16x8 kf =
                *(const bf16x8*)&Klds[buf][row * 64 + (((2 * ks + hd) ^ (row & 7)) << 3)];
            sac[kb] = MFMA32(kf, qf[ks], sac[kb]);
          }
        // ---- causal mask (diagonal tiles only) ----
        if (kv0 + 63 > q0w) {
#pragma unroll
          for (int kb = 0; kb < 2; ++kb)
#pragma unroll
            for (int r = 0; r < 16; ++r) {
              const int kv = kv0 + kb * 32 + (r & 3) + 8 * (r >> 2) + 4 * hd;
              if (kv > myq) sac[kb][r] = -3.0e38f;
            }
        }
        // ---- online softmax (q row lane-local; halves combined via 1 shfl) ----
        float pm4[8], sm4[8];
#pragma unroll
        for (int g = 0; g < 8; ++g) {
          const int kb = g >> 2, r = (g & 3) * 4;
          pm4[g] = fmaxf(fmaxf(sac[kb][r], sac[kb][r + 1]),
                         fmaxf(sac[kb][r + 2], sac[kb][r + 3]));
        }
        float pm = fmaxf(fmaxf(fmaxf(pm4[0], pm4[1]), fmaxf(pm4[2], pm4[3])),
                         fmaxf(fmaxf(pm4[4], pm4[5]), fmaxf(pm4[6], pm4[7])));
        pm = fmaxf(pm, __shfl_xor(pm, 32, 64));
        if (!__all(pm <= m + 8.f)) {           // T13 defer-max: rescale only on real growth
          const float mnew = fmaxf(m, pm);
          const float sc = __builtin_amdgcn_exp2f(m - mnew);
          l *= sc;
          yac[0] *= sc;
          yac[1] *= sc;
          m = mnew;
        }
#pragma unroll
        for (int kb = 0; kb < 2; ++kb)
#pragma unroll
          for (int r = 0; r < 16; ++r)
            sac[kb][r] = __builtin_amdgcn_exp2f(sac[kb][r] - m);
#pragma unroll
        for (int g = 0; g < 8; ++g) {
          const int kb = g >> 2, r = (g & 3) * 4;
          sm4[g] = (sac[kb][r] + sac[kb][r + 1]) + (sac[kb][r + 2] + sac[kb][r + 3]);
        }
        float rs = ((sm4[0] + sm4[1]) + (sm4[2] + sm4[3])) +
                   ((sm4[4] + sm4[5]) + (sm4[6] + sm4[7]));
        rs += __shfl_xor(rs, 32, 64);
        l += rs;
        // ---- pack P^T B-frags in-register + PV ----
#pragma unroll
        for (int ks = 0; ks < 4; ++ks) {
          const int kb = ks >> 1;
          const int Bv = 8 * (ks & 1);
          const unsigned p0 = pkbf16(sac[kb][Bv + 0], sac[kb][Bv + 1]);
          const unsigned p1 = pkbf16(sac[kb][Bv + 2], sac[kb][Bv + 3]);
          const unsigned p2 = pkbf16(sac[kb][Bv + 4], sac[kb][Bv + 5]);
          const unsigned p3 = pkbf16(sac[kb][Bv + 6], sac[kb][Bv + 7]);
          const unsigned xf0 = hd ? p0 : p2, xf1 = hd ? p1 : p3;
          const unsigned rc0 = __shfl_xor(xf0, 32, 64);
          const unsigned rc1 = __shfl_xor(xf1, 32, 64);
          union { unsigned u[4]; bf16x8 v; } pu;
          pu.u[0] = hd ? rc0 : p0;
          pu.u[1] = hd ? rc1 : p1;
          pu.u[2] = hd ? p2 : rc0;
          pu.u[3] = hd ? p3 : rc1;
#pragma unroll
          for (int db = 0; db < 2; ++db) {
            const int row = db * 32 + l31;
            const bf16x8 vf =
                *(const bf16x8*)&Vlds[buf][row * 64 + (((2 * ks + hd) ^ (row & 7)) << 3)];
            yac[db] = MFMA32(vf, pu.v, yac[db]);
          }
        }
      }

      if (kt + 1 < NT) wrLDS(buf ^ 1);         // write-late: regs -> other LDS buffer
      __syncthreads();
    }

    // ---- epilogue: lane holds full y row for q = myq ----
    const float inv = __builtin_amdgcn_rcpf(l);
    bf16_t* yp = y + (bS + myq) * (long)H_ + h * 64;
#pragma unroll
    for (int db = 0; db < 2; ++db)
#pragma unroll
      for (int g = 0; g < 4; ++g) {
        bf16x4 o;
        o[0] = (bf16_t)(yac[db][4 * g + 0] * inv);
        o[1] = (bf16_t)(yac[db][4 * g + 1] * inv);
        o[2] = (bf16_t)(yac[db][4 * g + 2] * inv);
        o[3] = (bf16_t)(yac[db][4 * g + 3] * inv);
        *(bf16x4*)(yp + db * 32 + 8 * g + 4 * hd) = o;
      }
  }
}

extern "C" void kernel_launch(void* const* d_in, const int* in_sizes, int n_in,
                              void* d_out, int out_size, void* d_ws, size_t ws_size,
                              hipStream_t stream) {
  const float* hs = (const float*)d_in[0];
  const float* cosb = (const float*)d_in[1];
  const float* sinb = (const float*)d_in[2];
  const float* Wq = (const float*)d_in[3];
  const float* Wk = (const float*)d_in[4];
  const float* Wv = (const float*)d_in[5];
  const float* Wo = (const float*)d_in[6];
  float* out = (float*)d_out;

  char* ws = (char*)d_ws;
  bf16_t* hsb  = (bf16_t*)(ws);                 // 16,777,216 B
  bf16_t* wqkv = (bf16_t*)(ws + 16777216);      // 12,582,912 B
  bf16_t* wo   = (bf16_t*)(ws + 29360128);      //  8,388,608 B
  bf16_t* qkv  = (bf16_t*)(ws + 37748736);      // 25,165,824 B
  bf16_t* vT   = (bf16_t*)(ws + 62914560);      //  4,194,304 B
  bf16_t* yb   = (bf16_t*)(ws + 67108864);      // 16,777,216 B

  cvt_kernel<<<4096, 256, 0, stream>>>(hs, hsb, 1048576);
  cvt_kernel<<<2048, 256, 0, stream>>>(Wq, wqkv, 524288);
  cvt_kernel<<<512, 256, 0, stream>>>(Wk, wqkv + 2048 * 2048, 131072);
  cvt_kernel<<<512, 256, 0, stream>>>(Wv, wqkv + 2560 * 2048, 131072);
  cvt_kernel<<<2048, 256, 0, stream>>>(Wo, wo, 524288);

  gemm_bt<true><<<dim3(24, 32), 256, 0, stream>>>(hsb, wqkv, nullptr, qkv,
                                                  M_ROWS, NQKV, H_);
  rope_kernel<<<20480, 256, 0, stream>>>(qkv, cosb, sinb);
  v_transpose<<<8192, 256, 0, stream>>>(qkv, vT);
  attn32_kernel<<<dim3(8, 32, 2), 256, 0, stream>>>(qkv, vT, yb);
  gemm_bt<false><<<dim3(16, 32), 256, 0, stream>>>(yb, wo, out, nullptr,
                                                   M_ROWS, H_, H_);
}